// Round 3
// baseline (1304.293 us; speedup 1.0000x reference)
//
#include <hip/hip_runtime.h>

#define BB 8
#define XX 256
#define CC 256
#define TC 8          // c-rows per k_all block
#define TCE 4         // c-rows per epilogue call (epilogue unchanged from R7)
#define G  8          // x-group size for the register double-buffer pipeline
#define NCH 4         // x-chunks; matches R7's SPLIT=4 fold tree bitwise
#define XCH (XX / NCH)

// R10: fix R9's scratch spill.
// R9 counters: FETCH 1.21 GB + WRITE 592 MB per k_all dispatch vs 134 MB
// requested loads and ~2 MB of atomic writes -> the 592 MB can only be
// scratch spill traffic (per-lane 4B, uncoalesced), which also explains
// VALUBusy 0.7% and 1128 us. Cause: FOUR G=8 buffer arrays (32 floats)
// live across the double-buffer + 9 accs + 8 w + 2 base pointers in a
// 4x-unrolled chunk loop. R7's proven k_dist pipeline held TWO arrays.
// Fix: fuse amp+ph -> u at LOAD time (u = wa*a + wp*p, identical
// expression/bits), so the double-buffer is 8 floats per buffer, and pin
// __launch_bounds__(256,4) like R7's k_dist (128-VGPR cap, ~60 regs live).
// Everything else (chunk order, fold tree, epilogue) is bitwise R9 = R7.

// ---------------- shared epilogue (bitwise R5..R9) ----------------

__device__ __forceinline__ void epilogue(
    float dist0, float dist1, float dist2, float dist3,
    int b, int c0, int d, const float* __restrict__ gu,
    float* __restrict__ out, float (*wmax)[4])
{
    float ed[TCE];
    ed[0] = (d == c0)     ? 0.0f : __fdiv_rn(1.0f, __fadd_rn(dist0, 1e-10f));
    ed[1] = (d == c0 + 1) ? 0.0f : __fdiv_rn(1.0f, __fadd_rn(dist1, 1e-10f));
    ed[2] = (d == c0 + 2) ? 0.0f : __fdiv_rn(1.0f, __fadd_rn(dist2, 1e-10f));
    ed[3] = (d == c0 + 3) ? 0.0f : __fdiv_rn(1.0f, __fadd_rn(dist3, 1e-10f));

    const int wave = threadIdx.x >> 6;
    const int lane = threadIdx.x & 63;
#pragma unroll
    for (int j = 0; j < TCE; ++j) {
        float v = ed[j];
#pragma unroll
        for (int m = 1; m < 64; m <<= 1) v = fmaxf(v, __shfl_xor(v, m));
        if (lane == 0) wmax[j][wave] = v;
    }
    __syncthreads();

#pragma unroll
    for (int j = 0; j < TCE; ++j) {
        const int c = c0 + j;
        float em = fmaxf(fmaxf(wmax[j][0], wmax[j][1]), fmaxf(wmax[j][2], wmax[j][3]));
        float p;
        if (d == c) {
            p = 0.99f;
        } else {
            p = __fmul_rn(__fdiv_rn(ed[j], em), 0.99f);
        }
        float logit = logf(__fdiv_rn(p, __fsub_rn(1.0f, p)));

        const float2 g2 = *(const float2*)(gu + (((size_t)b * CC + c) * CC + d) * 2);
        float g0 = -logf(-logf(g2.x));
        float g1 = -logf(-logf(g2.y));

        float a0 = __fadd_rn(logit, g0);
        float a1 = __fadd_rn(-logit, g1);
        float m  = fmaxf(a0, a1);
        float e0 = expf(__fsub_rn(a0, m));
        float e1 = expf(__fsub_rn(a1, m));
        float s  = __fadd_rn(e0, e1);
        float y0 = __fdiv_rn(e0, s);
        float y1 = __fdiv_rn(e1, s);
        if (y0 > y1) {
            atomicAdd(&out[(size_t)c * CC + d], 0.125f);
        }
    }
}

// ---------------- out zeroing (replaces memset dispatch) ----------------

__global__ __launch_bounds__(256) void k_zero(float* __restrict__ out)
{
    // 64 blocks * 256 threads * 16 B = 256 KB, exact cover of out
    ((float4*)out)[blockIdx.x * 256 + threadIdx.x] = make_float4(0.f, 0.f, 0.f, 0.f);
}

// ---------------- fused kernel ----------------

// Load 8 amp + 8 ph column values, fuse immediately into u = wa*a + wp*p.
// Load temps are macro-local: live only between the 16 loads and the 8
// fuse-FMAs, so the persistent double-buffer is 8 floats per buffer.
#define ULOADU(BU, GIDX) {                                       \
    const float* _a = aChunk + (size_t)(GIDX) * G * CC;          \
    const float* _p = pChunk + (size_t)(GIDX) * G * CC;          \
    float _ta[G], _tp[G];                                        \
    _Pragma("unroll")                                            \
    for (int i = 0; i < G; ++i) {                                \
        _ta[i] = _a[(size_t)i * CC];                             \
        _tp[i] = _p[(size_t)i * CC];                             \
    }                                                            \
    _Pragma("unroll")                                            \
    for (int i = 0; i < G; ++i)                                  \
        BU[i] = __fadd_rn(__fmul_rn(wa, _ta[i]),                 \
                          __fmul_rn(wp, _tp[i]));                \
    }

#define UCOMPU(BU, GIDX) {                                       \
    const int _xb = xc0 + (GIDX) * G;                            \
    _Pragma("unroll")                                            \
    for (int i = 0; i < G; ++i) {                                \
        const float udv = BU[i];                                 \
        const float4 cA = colsU[_xb + i][0];                     \
        const float4 cB = colsU[_xb + i][1];                     \
        gacc0 = fmaf(cA.x, udv, gacc0);                          \
        gacc1 = fmaf(cA.y, udv, gacc1);                          \
        gacc2 = fmaf(cA.z, udv, gacc2);                          \
        gacc3 = fmaf(cA.w, udv, gacc3);                          \
        gacc4 = fmaf(cB.x, udv, gacc4);                          \
        gacc5 = fmaf(cB.y, udv, gacc5);                          \
        gacc6 = fmaf(cB.z, udv, gacc6);                          \
        gacc7 = fmaf(cB.w, udv, gacc7);                          \
        sacc  = fmaf(udv, udv, sacc);                            \
    } }

__global__ __launch_bounds__(256, 4) void k_all(
    const float* __restrict__ amp, const float* __restrict__ ph,
    const float* __restrict__ A,   const float* __restrict__ wAp,
    const float* __restrict__ wPp, const float* __restrict__ gu,
    float* __restrict__ out)
{
    const int d  = threadIdx.x;
    const int c0 = blockIdx.x * TC;
    const int b  = blockIdx.y;

    const float wa = wAp[0];
    const float wp = wPp[0];

    __shared__ float4 colsU[XX][2];   // u[b, x, c0..c0+7], 8 KB
    __shared__ float  sS[CC];         // per-chunk S_d exchange
    __shared__ float  wmax[TCE][4];

    // Stage u columns c0..c0+7 for all x (same formula -> same bits)
    {
        const int x = threadIdx.x;
        const size_t base = ((size_t)b * XX + x) * CC + c0;
        const float4 a0 = *(const float4*)(amp + base);
        const float4 p0 = *(const float4*)(ph  + base);
        const float4 a1 = *(const float4*)(amp + base + 4);
        const float4 p1 = *(const float4*)(ph  + base + 4);
        float4 u0, u1;
        u0.x = __fadd_rn(__fmul_rn(wa, a0.x), __fmul_rn(wp, p0.x));
        u0.y = __fadd_rn(__fmul_rn(wa, a0.y), __fmul_rn(wp, p0.y));
        u0.z = __fadd_rn(__fmul_rn(wa, a0.z), __fmul_rn(wp, p0.z));
        u0.w = __fadd_rn(__fmul_rn(wa, a0.w), __fmul_rn(wp, p0.w));
        u1.x = __fadd_rn(__fmul_rn(wa, a1.x), __fmul_rn(wp, p1.x));
        u1.y = __fadd_rn(__fmul_rn(wa, a1.y), __fmul_rn(wp, p1.y));
        u1.z = __fadd_rn(__fmul_rn(wa, a1.z), __fmul_rn(wp, p1.z));
        u1.w = __fadd_rn(__fmul_rn(wa, a1.w), __fmul_rn(wp, p1.w));
        colsU[x][0] = u0;
        colsU[x][1] = u1;
    }
    __syncthreads();

    const float* aCol = amp + (size_t)b * XX * CC + d;
    const float* pCol = ph  + (size_t)b * XX * CC + d;

    float w0 = 0.f, w1 = 0.f, w2 = 0.f, w3 = 0.f;
    float w4 = 0.f, w5 = 0.f, w6 = 0.f, w7 = 0.f;

#pragma unroll
    for (int h = 0; h < NCH; ++h) {
        const int xc0 = h * XCH;
        const float* aChunk = aCol + (size_t)xc0 * CC;
        const float* pChunk = pCol + (size_t)xc0 * CC;

        float gacc0 = 0.f, gacc1 = 0.f, gacc2 = 0.f, gacc3 = 0.f;
        float gacc4 = 0.f, gacc5 = 0.f, gacc6 = 0.f, gacc7 = 0.f, sacc = 0.f;

        constexpr int NGH = XCH / G;   // 8
        float b0U[G], b1U[G];
        ULOADU(b0U, 0)
        for (int g = 0; g + 2 < NGH; g += 2) {
            ULOADU(b1U, g + 1)
            UCOMPU(b0U, g)
            ULOADU(b0U, g + 2)
            UCOMPU(b1U, g + 1)
        }
        ULOADU(b1U, NGH - 1)
        UCOMPU(b0U, NGH - 2)
        UCOMPU(b1U, NGH - 1)

        __syncthreads();          // previous chunk's sS readers are done
        sS[d] = sacc;
        __syncthreads();

        // per-chunk partial, identical chain to R7's k_dist store
        const float t0 = fmaf(-2.0f, gacc0, __fadd_rn(sS[c0 + 0], sacc));
        const float t1 = fmaf(-2.0f, gacc1, __fadd_rn(sS[c0 + 1], sacc));
        const float t2 = fmaf(-2.0f, gacc2, __fadd_rn(sS[c0 + 2], sacc));
        const float t3 = fmaf(-2.0f, gacc3, __fadd_rn(sS[c0 + 3], sacc));
        const float t4 = fmaf(-2.0f, gacc4, __fadd_rn(sS[c0 + 4], sacc));
        const float t5 = fmaf(-2.0f, gacc5, __fadd_rn(sS[c0 + 5], sacc));
        const float t6 = fmaf(-2.0f, gacc6, __fadd_rn(sS[c0 + 6], sacc));
        const float t7 = fmaf(-2.0f, gacc7, __fadd_rn(sS[c0 + 7], sacc));
        if (h == 0) {
            w0 = t0; w1 = t1; w2 = t2; w3 = t3;
            w4 = t4; w5 = t5; w6 = t6; w7 = t7;
        } else {
            // same left-associated fold as R7's k_epi: ((w0+w1)+w2)+w3
            w0 = __fadd_rn(w0, t0); w1 = __fadd_rn(w1, t1);
            w2 = __fadd_rn(w2, t2); w3 = __fadd_rn(w3, t3);
            w4 = __fadd_rn(w4, t4); w5 = __fadd_rn(w5, t5);
            w6 = __fadd_rn(w6, t6); w7 = __fadd_rn(w7, t7);
        }
    }

    const float dAd  = A[(size_t)d * CC + d];
    const float dAd2 = __fmul_rn(dAd, dAd);

    epilogue(__fmul_rn(dAd2, w0), __fmul_rn(dAd2, w1),
             __fmul_rn(dAd2, w2), __fmul_rn(dAd2, w3),
             b, c0, d, gu, out, wmax);
    __syncthreads();   // wmax reuse barrier between the two epilogue calls
    epilogue(__fmul_rn(dAd2, w4), __fmul_rn(dAd2, w5),
             __fmul_rn(dAd2, w6), __fmul_rn(dAd2, w7),
             b, c0 + 4, d, gu, out, wmax);
}

extern "C" void kernel_launch(void* const* d_in, const int* in_sizes, int n_in,
                              void* d_out, int out_size, void* d_ws, size_t ws_size,
                              hipStream_t stream) {
    const float* amp = (const float*)d_in[0];
    const float* ph  = (const float*)d_in[1];
    const float* A   = (const float*)d_in[2];
    const float* wa  = (const float*)d_in[3];
    const float* wp  = (const float*)d_in[4];
    const float* gu  = (const float*)d_in[5];
    float* out = (float*)d_out;

    (void)d_ws; (void)ws_size;   // R10: workspace intentionally unused

    k_zero<<<(CC * CC / 4) / 256, 256, 0, stream>>>(out);
    dim3 g(CC / TC, BB);
    k_all<<<g, 256, 0, stream>>>(amp, ph, A, wa, wp, gu, out);
}

// Round 4
// 91.176 us; speedup vs baseline: 14.3052x; 14.3052x over previous
//
#include <hip/hip_runtime.h>

#define BB 8
#define XX 256
#define CC 256
#define TC 8          // c-rows per k_all block
#define TCE 4         // c-rows per epilogue call (epilogue unchanged from R7)
#define NCH 4         // x-chunks; matches R7's SPLIT=4 fold tree bitwise
#define XCH (XX / NCH)   // 64 x-rows per chunk

// R11: kill the scratch arrays by restructuring around an LDS x-tile.
// R9/R10 evidence: FETCH 1.2-1.4 GB + WRITE 580-660 MB per k_all dispatch,
// nearly invariant to the VGPR cap (128 -> 64 moved it only 15%) -> the
// register-pipeline's private arrays (_ta/_tp temps, b0U/b1U) are living in
// scratch (fixed backing-store traffic), not spilling marginally. The same
// pipeline compiled clean as R7's small k_dist, but not inside this big
// fused function. R11 has NO private arrays in the hot path:
//   per chunk: cooperative stage of u[b, x0:x0+64, :] into a 64 KB LDS tile
//   (float4 global loads, u = wa*a + wp*p fused at stage time), then
//   d-column reads (lane-consecutive b32, conflict-free) and c-quad reads
//   (two b128 broadcasts, same-address = free) straight from LDS.
// Grid is 256 blocks = 1 block/CU, so 65 KB LDS costs no occupancy.
// Per-(c,d) FMA order over x, chunk structure, sS exchange, fold tree and
// epilogue are unchanged -> bitwise identical to R7..R10 (absmax 0.0).

// ---------------- shared epilogue (bitwise R5..R10) ----------------

__device__ __forceinline__ void epilogue(
    float dist0, float dist1, float dist2, float dist3,
    int b, int c0, int d, const float* __restrict__ gu,
    float* __restrict__ out, float (*wmax)[4])
{
    float ed[TCE];
    ed[0] = (d == c0)     ? 0.0f : __fdiv_rn(1.0f, __fadd_rn(dist0, 1e-10f));
    ed[1] = (d == c0 + 1) ? 0.0f : __fdiv_rn(1.0f, __fadd_rn(dist1, 1e-10f));
    ed[2] = (d == c0 + 2) ? 0.0f : __fdiv_rn(1.0f, __fadd_rn(dist2, 1e-10f));
    ed[3] = (d == c0 + 3) ? 0.0f : __fdiv_rn(1.0f, __fadd_rn(dist3, 1e-10f));

    const int wave = threadIdx.x >> 6;
    const int lane = threadIdx.x & 63;
#pragma unroll
    for (int j = 0; j < TCE; ++j) {
        float v = ed[j];
#pragma unroll
        for (int m = 1; m < 64; m <<= 1) v = fmaxf(v, __shfl_xor(v, m));
        if (lane == 0) wmax[j][wave] = v;
    }
    __syncthreads();

#pragma unroll
    for (int j = 0; j < TCE; ++j) {
        const int c = c0 + j;
        float em = fmaxf(fmaxf(wmax[j][0], wmax[j][1]), fmaxf(wmax[j][2], wmax[j][3]));
        float p;
        if (d == c) {
            p = 0.99f;
        } else {
            p = __fmul_rn(__fdiv_rn(ed[j], em), 0.99f);
        }
        float logit = logf(__fdiv_rn(p, __fsub_rn(1.0f, p)));

        const float2 g2 = *(const float2*)(gu + (((size_t)b * CC + c) * CC + d) * 2);
        float g0 = -logf(-logf(g2.x));
        float g1 = -logf(-logf(g2.y));

        float a0 = __fadd_rn(logit, g0);
        float a1 = __fadd_rn(-logit, g1);
        float m  = fmaxf(a0, a1);
        float e0 = expf(__fsub_rn(a0, m));
        float e1 = expf(__fsub_rn(a1, m));
        float s  = __fadd_rn(e0, e1);
        float y0 = __fdiv_rn(e0, s);
        float y1 = __fdiv_rn(e1, s);
        if (y0 > y1) {
            atomicAdd(&out[(size_t)c * CC + d], 0.125f);
        }
    }
}

// ---------------- out zeroing (replaces memset dispatch) ----------------

__global__ __launch_bounds__(256) void k_zero(float* __restrict__ out)
{
    // 64 blocks * 256 threads * 16 B = 256 KB, exact cover of out
    ((float4*)out)[blockIdx.x * 256 + threadIdx.x] = make_float4(0.f, 0.f, 0.f, 0.f);
}

// ---------------- fused kernel ----------------

__global__ __launch_bounds__(256) void k_all(
    const float* __restrict__ amp, const float* __restrict__ ph,
    const float* __restrict__ A,   const float* __restrict__ wAp,
    const float* __restrict__ wPp, const float* __restrict__ gu,
    float* __restrict__ out)
{
    const int d  = threadIdx.x;
    const int c0 = blockIdx.x * TC;
    const int b  = blockIdx.y;

    const float wa = wAp[0];
    const float wp = wPp[0];

    __shared__ float uT[XCH * CC];    // u[b, x0:x0+64, 0:256], 64 KB
    __shared__ float sS[CC];          // per-chunk S_d exchange
    __shared__ float wmax[TCE][4];

    float w0 = 0.f, w1 = 0.f, w2 = 0.f, w3 = 0.f;
    float w4 = 0.f, w5 = 0.f, w6 = 0.f, w7 = 0.f;

    for (int h = 0; h < NCH; ++h) {
        // ---- stage u[b, h*64:(h+1)*64, :] into LDS (fused at load) ----
        {
            const float4* aS = (const float4*)(amp + ((size_t)b * XX + h * XCH) * CC);
            const float4* pS = (const float4*)(ph  + ((size_t)b * XX + h * XCH) * CC);
            float4* uT4 = (float4*)uT;
#pragma unroll 8
            for (int k = 0; k < (XCH * CC / 4) / 256; ++k) {   // 16 iters
                const int idx = k * 256 + threadIdx.x;
                const float4 a = aS[idx];
                const float4 p = pS[idx];
                float4 u;
                u.x = __fadd_rn(__fmul_rn(wa, a.x), __fmul_rn(wp, p.x));
                u.y = __fadd_rn(__fmul_rn(wa, a.y), __fmul_rn(wp, p.y));
                u.z = __fadd_rn(__fmul_rn(wa, a.z), __fmul_rn(wp, p.z));
                u.w = __fadd_rn(__fmul_rn(wa, a.w), __fmul_rn(wp, p.w));
                uT4[idx] = u;
            }
        }
        __syncthreads();

        // ---- gram accumulation over this chunk's 64 x, ascending ----
        float gacc0 = 0.f, gacc1 = 0.f, gacc2 = 0.f, gacc3 = 0.f;
        float gacc4 = 0.f, gacc5 = 0.f, gacc6 = 0.f, gacc7 = 0.f, sacc = 0.f;
#pragma unroll 4
        for (int x = 0; x < XCH; ++x) {
            const float* row = uT + x * CC;
            const float ud  = row[d];                           // b32, lane-consecutive
            const float4 cA = *(const float4*)(row + c0);       // b128 broadcast
            const float4 cB = *(const float4*)(row + c0 + 4);   // b128 broadcast
            gacc0 = fmaf(cA.x, ud, gacc0);
            gacc1 = fmaf(cA.y, ud, gacc1);
            gacc2 = fmaf(cA.z, ud, gacc2);
            gacc3 = fmaf(cA.w, ud, gacc3);
            gacc4 = fmaf(cB.x, ud, gacc4);
            gacc5 = fmaf(cB.y, ud, gacc5);
            gacc6 = fmaf(cB.z, ud, gacc6);
            gacc7 = fmaf(cB.w, ud, gacc7);
            sacc  = fmaf(ud, ud, sacc);
        }
        __syncthreads();          // compute done: uT reusable, sS writable
        sS[d] = sacc;
        __syncthreads();

        // per-chunk partial, identical chain to R7's k_dist store
        const float t0 = fmaf(-2.0f, gacc0, __fadd_rn(sS[c0 + 0], sacc));
        const float t1 = fmaf(-2.0f, gacc1, __fadd_rn(sS[c0 + 1], sacc));
        const float t2 = fmaf(-2.0f, gacc2, __fadd_rn(sS[c0 + 2], sacc));
        const float t3 = fmaf(-2.0f, gacc3, __fadd_rn(sS[c0 + 3], sacc));
        const float t4 = fmaf(-2.0f, gacc4, __fadd_rn(sS[c0 + 4], sacc));
        const float t5 = fmaf(-2.0f, gacc5, __fadd_rn(sS[c0 + 5], sacc));
        const float t6 = fmaf(-2.0f, gacc6, __fadd_rn(sS[c0 + 6], sacc));
        const float t7 = fmaf(-2.0f, gacc7, __fadd_rn(sS[c0 + 7], sacc));
        if (h == 0) {
            w0 = t0; w1 = t1; w2 = t2; w3 = t3;
            w4 = t4; w5 = t5; w6 = t6; w7 = t7;
        } else {
            // same left-associated fold as R7's k_epi: ((w0+w1)+w2)+w3
            w0 = __fadd_rn(w0, t0); w1 = __fadd_rn(w1, t1);
            w2 = __fadd_rn(w2, t2); w3 = __fadd_rn(w3, t3);
            w4 = __fadd_rn(w4, t4); w5 = __fadd_rn(w5, t5);
            w6 = __fadd_rn(w6, t6); w7 = __fadd_rn(w7, t7);
        }
        // next chunk's sS write is two barriers away -> sS reads above are safe
    }

    const float dAd  = A[(size_t)d * CC + d];
    const float dAd2 = __fmul_rn(dAd, dAd);

    epilogue(__fmul_rn(dAd2, w0), __fmul_rn(dAd2, w1),
             __fmul_rn(dAd2, w2), __fmul_rn(dAd2, w3),
             b, c0, d, gu, out, wmax);
    __syncthreads();   // wmax reuse barrier between the two epilogue calls
    epilogue(__fmul_rn(dAd2, w4), __fmul_rn(dAd2, w5),
             __fmul_rn(dAd2, w6), __fmul_rn(dAd2, w7),
             b, c0 + 4, d, gu, out, wmax);
}

extern "C" void kernel_launch(void* const* d_in, const int* in_sizes, int n_in,
                              void* d_out, int out_size, void* d_ws, size_t ws_size,
                              hipStream_t stream) {
    const float* amp = (const float*)d_in[0];
    const float* ph  = (const float*)d_in[1];
    const float* A   = (const float*)d_in[2];
    const float* wa  = (const float*)d_in[3];
    const float* wp  = (const float*)d_in[4];
    const float* gu  = (const float*)d_in[5];
    float* out = (float*)d_out;

    (void)d_ws; (void)ws_size;   // R11: workspace intentionally unused

    k_zero<<<(CC * CC / 4) / 256, 256, 0, stream>>>(out);
    dim3 g(CC / TC, BB);
    k_all<<<g, 256, 0, stream>>>(amp, ph, A, wa, wp, gu, out);
}

// Round 5
// 87.077 us; speedup vs baseline: 14.9787x; 1.0471x over previous
//
#include <hip/hip_runtime.h>

#define BB 8
#define XX 256
#define CC 256
#define TC 4          // c-rows per k_all block (R12: was 8; halves per-x LDS work)
#define TCE 4         // c-rows per epilogue call (epilogue unchanged from R7)
#define NCH 4         // x-chunks; matches R7's SPLIT=4 fold tree bitwise
#define XCH (XX / NCH)   // 64 x-rows per chunk

// R12: occupancy + LDS-issue fix on the R11 structure.
// R11 post-mortem: k_all left the top-5 (scratch fixed, absmax 0.0) but the
// 256 MiB ws poison fill (~40.6 us) appeared ANYWAY -> the fill is
// unconditional; it is a hard floor and ws use is free. k_all itself ran
// ~35-40 us vs ~8-10 us roofline because grid=256 blocks = 1 block/CU =
// 1 wave/SIMD (zero latency hiding) and the shared LDS pipe carried
// 64 b32 + 128 b128 per wave per chunk between barriers.
// R12: TC=4 -> grid (64,8) = 512 blocks = 2 blocks/CU (LDS 66.6 KB x2 =
// 133 KB <= 160 KB, both resident; one block computes while the other
// barriers), per-x LDS drops to 1 b128 + 1 b32, FMAs 9 -> 5.
// Bitwise: per-(c,d) accumulation order, chunk fold, sS exchange, dAd^2,
// epilogue all unchanged -> absmax 0.0 expected.

// ---------------- shared epilogue (bitwise R5..R11) ----------------

__device__ __forceinline__ void epilogue(
    float dist0, float dist1, float dist2, float dist3,
    int b, int c0, int d, const float* __restrict__ gu,
    float* __restrict__ out, float (*wmax)[4])
{
    float ed[TCE];
    ed[0] = (d == c0)     ? 0.0f : __fdiv_rn(1.0f, __fadd_rn(dist0, 1e-10f));
    ed[1] = (d == c0 + 1) ? 0.0f : __fdiv_rn(1.0f, __fadd_rn(dist1, 1e-10f));
    ed[2] = (d == c0 + 2) ? 0.0f : __fdiv_rn(1.0f, __fadd_rn(dist2, 1e-10f));
    ed[3] = (d == c0 + 3) ? 0.0f : __fdiv_rn(1.0f, __fadd_rn(dist3, 1e-10f));

    const int wave = threadIdx.x >> 6;
    const int lane = threadIdx.x & 63;
#pragma unroll
    for (int j = 0; j < TCE; ++j) {
        float v = ed[j];
#pragma unroll
        for (int m = 1; m < 64; m <<= 1) v = fmaxf(v, __shfl_xor(v, m));
        if (lane == 0) wmax[j][wave] = v;
    }
    __syncthreads();

#pragma unroll
    for (int j = 0; j < TCE; ++j) {
        const int c = c0 + j;
        float em = fmaxf(fmaxf(wmax[j][0], wmax[j][1]), fmaxf(wmax[j][2], wmax[j][3]));
        float p;
        if (d == c) {
            p = 0.99f;
        } else {
            p = __fmul_rn(__fdiv_rn(ed[j], em), 0.99f);
        }
        float logit = logf(__fdiv_rn(p, __fsub_rn(1.0f, p)));

        const float2 g2 = *(const float2*)(gu + (((size_t)b * CC + c) * CC + d) * 2);
        float g0 = -logf(-logf(g2.x));
        float g1 = -logf(-logf(g2.y));

        float a0 = __fadd_rn(logit, g0);
        float a1 = __fadd_rn(-logit, g1);
        float m  = fmaxf(a0, a1);
        float e0 = expf(__fsub_rn(a0, m));
        float e1 = expf(__fsub_rn(a1, m));
        float s  = __fadd_rn(e0, e1);
        float y0 = __fdiv_rn(e0, s);
        float y1 = __fdiv_rn(e1, s);
        if (y0 > y1) {
            atomicAdd(&out[(size_t)c * CC + d], 0.125f);
        }
    }
}

// ---------------- out zeroing (replaces memset dispatch) ----------------

__global__ __launch_bounds__(256) void k_zero(float* __restrict__ out)
{
    // 64 blocks * 256 threads * 16 B = 256 KB, exact cover of out
    ((float4*)out)[blockIdx.x * 256 + threadIdx.x] = make_float4(0.f, 0.f, 0.f, 0.f);
}

// ---------------- fused kernel ----------------

__global__ __launch_bounds__(256) void k_all(
    const float* __restrict__ amp, const float* __restrict__ ph,
    const float* __restrict__ A,   const float* __restrict__ wAp,
    const float* __restrict__ wPp, const float* __restrict__ gu,
    float* __restrict__ out)
{
    const int d  = threadIdx.x;
    const int c0 = blockIdx.x * TC;
    const int b  = blockIdx.y;

    const float wa = wAp[0];
    const float wp = wPp[0];

    __shared__ float uT[XCH * CC];    // u[b, x0:x0+64, 0:256], 64 KB
    __shared__ float sS[CC];          // per-chunk S_d exchange
    __shared__ float wmax[TCE][4];

    float w0 = 0.f, w1 = 0.f, w2 = 0.f, w3 = 0.f;

    for (int h = 0; h < NCH; ++h) {
        // ---- stage u[b, h*64:(h+1)*64, :] into LDS (fused at load) ----
        {
            const float4* aS = (const float4*)(amp + ((size_t)b * XX + h * XCH) * CC);
            const float4* pS = (const float4*)(ph  + ((size_t)b * XX + h * XCH) * CC);
            float4* uT4 = (float4*)uT;
#pragma unroll 8
            for (int k = 0; k < (XCH * CC / 4) / 256; ++k) {   // 16 iters
                const int idx = k * 256 + threadIdx.x;
                const float4 a = aS[idx];
                const float4 p = pS[idx];
                float4 u;
                u.x = __fadd_rn(__fmul_rn(wa, a.x), __fmul_rn(wp, p.x));
                u.y = __fadd_rn(__fmul_rn(wa, a.y), __fmul_rn(wp, p.y));
                u.z = __fadd_rn(__fmul_rn(wa, a.z), __fmul_rn(wp, p.z));
                u.w = __fadd_rn(__fmul_rn(wa, a.w), __fmul_rn(wp, p.w));
                uT4[idx] = u;
            }
        }
        __syncthreads();

        // ---- gram accumulation over this chunk's 64 x, ascending ----
        float gacc0 = 0.f, gacc1 = 0.f, gacc2 = 0.f, gacc3 = 0.f, sacc = 0.f;
#pragma unroll 4
        for (int x = 0; x < XCH; ++x) {
            const float* row = uT + x * CC;
            const float ud  = row[d];                           // b32, lane-consecutive
            const float4 cA = *(const float4*)(row + c0);       // b128 broadcast
            gacc0 = fmaf(cA.x, ud, gacc0);
            gacc1 = fmaf(cA.y, ud, gacc1);
            gacc2 = fmaf(cA.z, ud, gacc2);
            gacc3 = fmaf(cA.w, ud, gacc3);
            sacc  = fmaf(ud, ud, sacc);
        }
        __syncthreads();          // compute done: uT reusable, sS writable
        sS[d] = sacc;
        __syncthreads();

        // per-chunk partial, identical chain to R7's k_dist store
        const float t0 = fmaf(-2.0f, gacc0, __fadd_rn(sS[c0 + 0], sacc));
        const float t1 = fmaf(-2.0f, gacc1, __fadd_rn(sS[c0 + 1], sacc));
        const float t2 = fmaf(-2.0f, gacc2, __fadd_rn(sS[c0 + 2], sacc));
        const float t3 = fmaf(-2.0f, gacc3, __fadd_rn(sS[c0 + 3], sacc));
        if (h == 0) {
            w0 = t0; w1 = t1; w2 = t2; w3 = t3;
        } else {
            // same left-associated fold as R7's k_epi: ((w0+w1)+w2)+w3
            w0 = __fadd_rn(w0, t0); w1 = __fadd_rn(w1, t1);
            w2 = __fadd_rn(w2, t2); w3 = __fadd_rn(w3, t3);
        }
        // next chunk's sS write is two barriers away -> sS reads above are safe
    }

    const float dAd  = A[(size_t)d * CC + d];
    const float dAd2 = __fmul_rn(dAd, dAd);

    epilogue(__fmul_rn(dAd2, w0), __fmul_rn(dAd2, w1),
             __fmul_rn(dAd2, w2), __fmul_rn(dAd2, w3),
             b, c0, d, gu, out, wmax);
}

extern "C" void kernel_launch(void* const* d_in, const int* in_sizes, int n_in,
                              void* d_out, int out_size, void* d_ws, size_t ws_size,
                              hipStream_t stream) {
    const float* amp = (const float*)d_in[0];
    const float* ph  = (const float*)d_in[1];
    const float* A   = (const float*)d_in[2];
    const float* wa  = (const float*)d_in[3];
    const float* wp  = (const float*)d_in[4];
    const float* gu  = (const float*)d_in[5];
    float* out = (float*)d_out;

    (void)d_ws; (void)ws_size;   // ws unused (poison fill happens regardless)

    k_zero<<<(CC * CC / 4) / 256, 256, 0, stream>>>(out);
    dim3 g(CC / TC, BB);
    k_all<<<g, 256, 0, stream>>>(amp, ph, A, wa, wp, gu, out);
}

// Round 7
// 84.493 us; speedup vs baseline: 15.4367x; 1.0306x over previous
//
#include <hip/hip_runtime.h>

#define BB 8
#define XX 256
#define CC 256
#define TC 4          // c-rows per k_go / k_all block
#define TCE 4         // c-rows per epilogue call (epilogue unchanged from R7)
#define NCH 4         // x-chunks; matches R7's SPLIT=4 fold tree bitwise
#define XCH (XX / NCH)   // 64 x-rows per chunk

// R14 = R13 resubmitted verbatim. R13 died with "Aborted (core dumped)" in
// pytest -- no absmax, no counters. Line-by-line audit found no fault
// candidate: k_u is R7's verbatim passing kernel; k_go max indices are
// 524287 < 524288 (in bounds); all barriers block-uniform; LDS 5.3 KB;
// no HIP API calls in kernel_launch; fallback path = R12's passing kernels.
// Given the session's infra history (R1 container failure; R13's 88 s
// acquire + 38 s push = sick container), the probable cause is a GPU-state
// flake. Re-running the identical experiment (R1->R2 precedent).
//
// R13 rationale: total = fill(40.6, unconditional ws poison) + ~11 us per
// dispatch + exec. R12's k_all ~23 us was LDS-pipe-bound (full 256-col
// u-tile staged per block, 64x redundant). R13/R14:
//   k_u  : u = wa*amp + wp*ph into ws; blocks 0..63 zero out  (k_zero gone)
//   k_go : stage only cols[256] = u[b,x,c0..c0+3] (4 KB, once); stream the
//          d-column from global (coalesced, u = 2 MB L2-resident); 5 FMA/x;
//          per-chunk sS exchange + fold; inline epilogue.
// Bitwise: identical u bits, identical per-(c,d) accumulation order, chunk
// fold, sS exchange, dAd^2, epilogue -> absmax 0.0 expected.

// ---------------- shared epilogue (bitwise R5..R12) ----------------

__device__ __forceinline__ void epilogue(
    float dist0, float dist1, float dist2, float dist3,
    int b, int c0, int d, const float* __restrict__ gu,
    float* __restrict__ out, float (*wmax)[4])
{
    float ed[TCE];
    ed[0] = (d == c0)     ? 0.0f : __fdiv_rn(1.0f, __fadd_rn(dist0, 1e-10f));
    ed[1] = (d == c0 + 1) ? 0.0f : __fdiv_rn(1.0f, __fadd_rn(dist1, 1e-10f));
    ed[2] = (d == c0 + 2) ? 0.0f : __fdiv_rn(1.0f, __fadd_rn(dist2, 1e-10f));
    ed[3] = (d == c0 + 3) ? 0.0f : __fdiv_rn(1.0f, __fadd_rn(dist3, 1e-10f));

    const int wave = threadIdx.x >> 6;
    const int lane = threadIdx.x & 63;
#pragma unroll
    for (int j = 0; j < TCE; ++j) {
        float v = ed[j];
#pragma unroll
        for (int m = 1; m < 64; m <<= 1) v = fmaxf(v, __shfl_xor(v, m));
        if (lane == 0) wmax[j][wave] = v;
    }
    __syncthreads();

#pragma unroll
    for (int j = 0; j < TCE; ++j) {
        const int c = c0 + j;
        float em = fmaxf(fmaxf(wmax[j][0], wmax[j][1]), fmaxf(wmax[j][2], wmax[j][3]));
        float p;
        if (d == c) {
            p = 0.99f;
        } else {
            p = __fmul_rn(__fdiv_rn(ed[j], em), 0.99f);
        }
        float logit = logf(__fdiv_rn(p, __fsub_rn(1.0f, p)));

        const float2 g2 = *(const float2*)(gu + (((size_t)b * CC + c) * CC + d) * 2);
        float g0 = -logf(-logf(g2.x));
        float g1 = -logf(-logf(g2.y));

        float a0 = __fadd_rn(logit, g0);
        float a1 = __fadd_rn(-logit, g1);
        float m  = fmaxf(a0, a1);
        float e0 = expf(__fsub_rn(a0, m));
        float e1 = expf(__fsub_rn(a1, m));
        float s  = __fadd_rn(e0, e1);
        float y0 = __fdiv_rn(e0, s);
        float y1 = __fdiv_rn(e1, s);
        if (y0 > y1) {
            atomicAdd(&out[(size_t)c * CC + d], 0.125f);
        }
    }
}

// ---------------- Path A: k_u + k_go (ws available) ----------------

// k_u: u = wa*amp + wp*ph for all B*X*C; blocks 0..63 also zero `out`.
// (R7's k_u, verbatim -> identical u bits.)
__global__ __launch_bounds__(256) void k_u(
    const float* __restrict__ amp, const float* __restrict__ ph,
    const float* __restrict__ wAp, const float* __restrict__ wPp,
    float* __restrict__ u, float* __restrict__ out)
{
    const float wa = wAp[0], wp = wPp[0];
    const int i = blockIdx.x * 256 + threadIdx.x;   // float4 index, exact cover
    const float4 a = ((const float4*)amp)[i];
    const float4 p = ((const float4*)ph)[i];
    float4 r;
    r.x = __fadd_rn(__fmul_rn(wa, a.x), __fmul_rn(wp, p.x));
    r.y = __fadd_rn(__fmul_rn(wa, a.y), __fmul_rn(wp, p.y));
    r.z = __fadd_rn(__fmul_rn(wa, a.z), __fmul_rn(wp, p.z));
    r.w = __fadd_rn(__fmul_rn(wa, a.w), __fmul_rn(wp, p.w));
    ((float4*)u)[i] = r;

    if (blockIdx.x < 64) {            // 64 blocks * 256 thr * 16B = 256 KB = out
        ((float4*)out)[blockIdx.x * 256 + threadIdx.x] = make_float4(0.f, 0.f, 0.f, 0.f);
    }
}

// k_go: gram from global u + epilogue, fused.
__global__ __launch_bounds__(256) void k_go(
    const float* __restrict__ u,  const float* __restrict__ A,
    const float* __restrict__ gu, float* __restrict__ out)
{
    const int d  = threadIdx.x;
    const int c0 = blockIdx.x * TC;
    const int b  = blockIdx.y;

    __shared__ float4 cols[XX];       // u[b, x, c0..c0+3], 4 KB
    __shared__ float  sS[CC];         // per-chunk S_d exchange
    __shared__ float  wmax[TCE][4];

    // stage the 4 c-columns (thread x = threadIdx.x loads one float4)
    cols[threadIdx.x] =
        *(const float4*)(u + ((size_t)b * XX + threadIdx.x) * CC + c0);
    __syncthreads();

    const float* ucol = u + (size_t)b * XX * CC + d;

    float w0 = 0.f, w1 = 0.f, w2 = 0.f, w3 = 0.f;

#pragma unroll
    for (int h = 0; h < NCH; ++h) {
        const int x0 = h * XCH;
        float gacc0 = 0.f, gacc1 = 0.f, gacc2 = 0.f, gacc3 = 0.f, sacc = 0.f;
#pragma unroll 4
        for (int x = 0; x < XCH; ++x) {
            const float ud  = ucol[(size_t)(x0 + x) * CC];  // coalesced global
            const float4 cA = cols[x0 + x];                 // LDS broadcast
            gacc0 = fmaf(cA.x, ud, gacc0);
            gacc1 = fmaf(cA.y, ud, gacc1);
            gacc2 = fmaf(cA.z, ud, gacc2);
            gacc3 = fmaf(cA.w, ud, gacc3);
            sacc  = fmaf(ud, ud, sacc);
        }
        __syncthreads();          // previous fold's sS reads are done
        sS[d] = sacc;
        __syncthreads();

        // per-chunk partial, identical chain to R7/R12
        const float t0 = fmaf(-2.0f, gacc0, __fadd_rn(sS[c0 + 0], sacc));
        const float t1 = fmaf(-2.0f, gacc1, __fadd_rn(sS[c0 + 1], sacc));
        const float t2 = fmaf(-2.0f, gacc2, __fadd_rn(sS[c0 + 2], sacc));
        const float t3 = fmaf(-2.0f, gacc3, __fadd_rn(sS[c0 + 3], sacc));
        if (h == 0) {
            w0 = t0; w1 = t1; w2 = t2; w3 = t3;
        } else {
            // same left-associated fold: ((w0+w1)+w2)+w3
            w0 = __fadd_rn(w0, t0); w1 = __fadd_rn(w1, t1);
            w2 = __fadd_rn(w2, t2); w3 = __fadd_rn(w3, t3);
        }
    }

    const float dAd  = A[(size_t)d * CC + d];
    const float dAd2 = __fmul_rn(dAd, dAd);

    epilogue(__fmul_rn(dAd2, w0), __fmul_rn(dAd2, w1),
             __fmul_rn(dAd2, w2), __fmul_rn(dAd2, w3),
             b, c0, d, gu, out, wmax);
}

// ---------------- Path B fallback: R12's k_zero + k_all (no ws) ----------------

__global__ __launch_bounds__(256) void k_zero(float* __restrict__ out)
{
    ((float4*)out)[blockIdx.x * 256 + threadIdx.x] = make_float4(0.f, 0.f, 0.f, 0.f);
}

__global__ __launch_bounds__(256) void k_all(
    const float* __restrict__ amp, const float* __restrict__ ph,
    const float* __restrict__ A,   const float* __restrict__ wAp,
    const float* __restrict__ wPp, const float* __restrict__ gu,
    float* __restrict__ out)
{
    const int d  = threadIdx.x;
    const int c0 = blockIdx.x * TC;
    const int b  = blockIdx.y;

    const float wa = wAp[0];
    const float wp = wPp[0];

    __shared__ float uT[XCH * CC];    // u[b, x0:x0+64, 0:256], 64 KB
    __shared__ float sS[CC];
    __shared__ float wmax[TCE][4];

    float w0 = 0.f, w1 = 0.f, w2 = 0.f, w3 = 0.f;

    for (int h = 0; h < NCH; ++h) {
        {
            const float4* aS = (const float4*)(amp + ((size_t)b * XX + h * XCH) * CC);
            const float4* pS = (const float4*)(ph  + ((size_t)b * XX + h * XCH) * CC);
            float4* uT4 = (float4*)uT;
#pragma unroll 8
            for (int k = 0; k < (XCH * CC / 4) / 256; ++k) {   // 16 iters
                const int idx = k * 256 + threadIdx.x;
                const float4 a = aS[idx];
                const float4 p = pS[idx];
                float4 uu;
                uu.x = __fadd_rn(__fmul_rn(wa, a.x), __fmul_rn(wp, p.x));
                uu.y = __fadd_rn(__fmul_rn(wa, a.y), __fmul_rn(wp, p.y));
                uu.z = __fadd_rn(__fmul_rn(wa, a.z), __fmul_rn(wp, p.z));
                uu.w = __fadd_rn(__fmul_rn(wa, a.w), __fmul_rn(wp, p.w));
                uT4[idx] = uu;
            }
        }
        __syncthreads();

        float gacc0 = 0.f, gacc1 = 0.f, gacc2 = 0.f, gacc3 = 0.f, sacc = 0.f;
#pragma unroll 4
        for (int x = 0; x < XCH; ++x) {
            const float* row = uT + x * CC;
            const float ud  = row[d];
            const float4 cA = *(const float4*)(row + c0);
            gacc0 = fmaf(cA.x, ud, gacc0);
            gacc1 = fmaf(cA.y, ud, gacc1);
            gacc2 = fmaf(cA.z, ud, gacc2);
            gacc3 = fmaf(cA.w, ud, gacc3);
            sacc  = fmaf(ud, ud, sacc);
        }
        __syncthreads();
        sS[d] = sacc;
        __syncthreads();

        const float t0 = fmaf(-2.0f, gacc0, __fadd_rn(sS[c0 + 0], sacc));
        const float t1 = fmaf(-2.0f, gacc1, __fadd_rn(sS[c0 + 1], sacc));
        const float t2 = fmaf(-2.0f, gacc2, __fadd_rn(sS[c0 + 2], sacc));
        const float t3 = fmaf(-2.0f, gacc3, __fadd_rn(sS[c0 + 3], sacc));
        if (h == 0) {
            w0 = t0; w1 = t1; w2 = t2; w3 = t3;
        } else {
            w0 = __fadd_rn(w0, t0); w1 = __fadd_rn(w1, t1);
            w2 = __fadd_rn(w2, t2); w3 = __fadd_rn(w3, t3);
        }
    }

    const float dAd  = A[(size_t)d * CC + d];
    const float dAd2 = __fmul_rn(dAd, dAd);

    epilogue(__fmul_rn(dAd2, w0), __fmul_rn(dAd2, w1),
             __fmul_rn(dAd2, w2), __fmul_rn(dAd2, w3),
             b, c0, d, gu, out, wmax);
}

extern "C" void kernel_launch(void* const* d_in, const int* in_sizes, int n_in,
                              void* d_out, int out_size, void* d_ws, size_t ws_size,
                              hipStream_t stream) {
    const float* amp = (const float*)d_in[0];
    const float* ph  = (const float*)d_in[1];
    const float* A   = (const float*)d_in[2];
    const float* wa  = (const float*)d_in[3];
    const float* wp  = (const float*)d_in[4];
    const float* gu  = (const float*)d_in[5];
    float* out = (float*)d_out;

    const size_t uElems = (size_t)BB * XX * CC;                // 2 MB
    if (ws_size >= uElems * sizeof(float)) {
        float* ud = (float*)d_ws;          // fully written by k_u before k_go
        k_u<<<(int)(uElems / 4 / 256), 256, 0, stream>>>(amp, ph, wa, wp, ud, out);
        dim3 g(CC / TC, BB);
        k_go<<<g, 256, 0, stream>>>(ud, A, gu, out);
    } else {
        k_zero<<<(CC * CC / 4) / 256, 256, 0, stream>>>(out);
        dim3 g(CC / TC, BB);
        k_all<<<g, 256, 0, stream>>>(amp, ph, A, wa, wp, gu, out);
    }
}